// Round 1
// baseline (4208.829 us; speedup 1.0000x reference)
//
#include <hip/hip_runtime.h>
#include <hip/hip_bf16.h>

// GCN encoder: out = GCNconv2( relu(GCNconv1(x)) )
// GCNconv(h,W,b) = D^-1/2 (A+I) D^-1/2 (h W) + b
//
// Pipeline (all f32):
//   1. deg[n] = 1 + #edges(dst==n);  dis = rsqrt(deg)
//   2. gemm1: t1 = x @ W1  [N,128]; epilogue: a1 = dis^2 * t1  (self-loop term)
//   3. agg1:  a1[dst] += dis[src]*dis[dst] * t1[src]   (atomics)
//   4. gemm2: t2 = relu(a1 + b1) @ W2 [N,64]; epilogue: out = dis^2 * t2 + b2
//   5. agg2:  out[dst] += dis[src]*dis[dst] * t2[src]  (atomics)

#define GCN_IN_C 256
#define GCN_HID  128
#define GCN_OUT  64

__global__ __launch_bounds__(256) void k_deg_init(float* __restrict__ deg, int n) {
  int i = blockIdx.x * 256 + threadIdx.x;
  if (i < n) deg[i] = 1.0f;  // self loop
}

__global__ __launch_bounds__(256) void k_deg_count(const int* __restrict__ dst,
                                                   float* __restrict__ deg, int e) {
  int i = blockIdx.x * 256 + threadIdx.x;
  if (i < e) unsafeAtomicAdd(&deg[dst[i]], 1.0f);
}

__global__ __launch_bounds__(256) void k_rsqrt(float* __restrict__ deg, int n) {
  int i = blockIdx.x * 256 + threadIdx.x;
  if (i < n) deg[i] = rsqrtf(deg[i]);
}

// Tiled f32 GEMM: T = X' @ W, X' = (IN_RELU_BIAS ? relu(X + inb) : X).
// Epilogue also writes OI = dis[m]^2 * T[m] (+ outb if OUT_BIAS).
// BM=64 rows/block, full NOUT cols, BK=32.
template<int K, int NOUT, bool IN_RELU_BIAS, bool OUT_BIAS>
__global__ __launch_bounds__(256) void k_gemm(
    const float* __restrict__ X, const float* __restrict__ W,
    const float* __restrict__ inb, const float* __restrict__ outb,
    const float* __restrict__ dis,
    float* __restrict__ T, float* __restrict__ OI, int M) {
  constexpr int BM = 64, BK = 32;
  constexpr int CPT = NOUT / 16;  // cols per thread (8 for 128, 4 for 64)
  __shared__ float xs[BM][BK + 1];
  __shared__ float ws[BK][NOUT];

  const int tid = threadIdx.x;
  const int m0 = blockIdx.x * BM;
  const int tx = tid & 15;
  const int ty = tid >> 4;

  float acc[4][CPT];
#pragma unroll
  for (int i = 0; i < 4; ++i)
#pragma unroll
    for (int j = 0; j < CPT; ++j) acc[i][j] = 0.0f;

  for (int k0 = 0; k0 < K; k0 += BK) {
    // ---- load X tile (BM x BK) as float4, 2 per thread
#pragma unroll
    for (int it = 0; it < (BM * BK) / (256 * 4); ++it) {
      int f4 = tid + it * 256;       // 0..511
      int r = f4 >> 3;               // BK/4 = 8 float4 per row
      int c4 = f4 & 7;
      int m = m0 + r;
      float4 v = make_float4(0.f, 0.f, 0.f, 0.f);
      if (m < M) v = *(const float4*)(X + (size_t)m * K + k0 + c4 * 4);
      if (IN_RELU_BIAS) {
        int kc = k0 + c4 * 4;
        v.x = fmaxf(v.x + inb[kc + 0], 0.f);
        v.y = fmaxf(v.y + inb[kc + 1], 0.f);
        v.z = fmaxf(v.z + inb[kc + 2], 0.f);
        v.w = fmaxf(v.w + inb[kc + 3], 0.f);
      }
      xs[r][c4 * 4 + 0] = v.x;
      xs[r][c4 * 4 + 1] = v.y;
      xs[r][c4 * 4 + 2] = v.z;
      xs[r][c4 * 4 + 3] = v.w;
    }
    // ---- load W tile (BK x NOUT) as float4
#pragma unroll
    for (int it = 0; it < (BK * NOUT) / (256 * 4); ++it) {
      int f4 = tid + it * 256;
      int r = f4 / (NOUT / 4);
      int c4 = f4 % (NOUT / 4);
      *(float4*)(&ws[r][c4 * 4]) =
          *(const float4*)(W + (size_t)(k0 + r) * NOUT + c4 * 4);
    }
    __syncthreads();
#pragma unroll
    for (int kk = 0; kk < BK; ++kk) {
      float a[4];
#pragma unroll
      for (int i = 0; i < 4; ++i) a[i] = xs[ty * 4 + i][kk];
      float b[CPT];
#pragma unroll
      for (int j = 0; j < CPT; ++j) b[j] = ws[kk][tx * CPT + j];
#pragma unroll
      for (int i = 0; i < 4; ++i)
#pragma unroll
        for (int j = 0; j < CPT; ++j) acc[i][j] = fmaf(a[i], b[j], acc[i][j]);
    }
    __syncthreads();
  }

  // ---- epilogue: write T and OI = dis^2 * T (+ outb)
#pragma unroll
  for (int i = 0; i < 4; ++i) {
    int m = m0 + ty * 4 + i;
    if (m >= M) continue;
    float d = dis[m];
    float dd = d * d;
    size_t base = (size_t)m * NOUT + tx * CPT;
#pragma unroll
    for (int j4 = 0; j4 < CPT / 4; ++j4) {
      float4 t, o;
      t.x = acc[i][j4 * 4 + 0];
      t.y = acc[i][j4 * 4 + 1];
      t.z = acc[i][j4 * 4 + 2];
      t.w = acc[i][j4 * 4 + 3];
      o.x = dd * t.x; o.y = dd * t.y; o.z = dd * t.z; o.w = dd * t.w;
      if (OUT_BIAS) {
        int c = tx * CPT + j4 * 4;
        o.x += outb[c + 0]; o.y += outb[c + 1];
        o.z += outb[c + 2]; o.w += outb[c + 3];
      }
      *(float4*)(T + base + j4 * 4) = t;
      *(float4*)(OI + base + j4 * 4) = o;
    }
  }
}

// Edge scatter: out[dst] += dis[src]*dis[dst] * t[src], C channels, float4 lanes.
template<int C>
__global__ __launch_bounds__(256) void k_agg_edge(
    const int* __restrict__ src, const int* __restrict__ dst,
    const float* __restrict__ t, const float* __restrict__ dis,
    float* __restrict__ out, int e) {
  constexpr int TPE = C / 4;  // threads per edge
  int gid = blockIdx.x * 256 + threadIdx.x;
  int ei = gid / TPE;
  int lane = gid % TPE;
  if (ei >= e) return;
  int s = src[ei];
  int d = dst[ei];
  float w = dis[s] * dis[d];
  float4 v = *(const float4*)(t + (size_t)s * C + lane * 4);
  float* o = out + (size_t)d * C + lane * 4;
  unsafeAtomicAdd(o + 0, w * v.x);
  unsafeAtomicAdd(o + 1, w * v.y);
  unsafeAtomicAdd(o + 2, w * v.z);
  unsafeAtomicAdd(o + 3, w * v.w);
}

extern "C" void kernel_launch(void* const* d_in, const int* in_sizes, int n_in,
                              void* d_out, int out_size, void* d_ws, size_t ws_size,
                              hipStream_t stream) {
  const float* x  = (const float*)d_in[0];
  const int*   ei = (const int*)d_in[1];
  const float* W1 = (const float*)d_in[2];
  const float* b1 = (const float*)d_in[3];
  const float* W2 = (const float*)d_in[4];
  const float* b2 = (const float*)d_in[5];
  float* out = (float*)d_out;

  const int N = in_sizes[0] / GCN_IN_C;  // 100000
  const int E = in_sizes[1] / 2;         // 1600000
  const int* src = ei;
  const int* dst = ei + E;

  // workspace layout: dis [N] | t1/t2 [N*HID] | a1 [N*HID]
  char* ws = (char*)d_ws;
  float* dis = (float*)ws;
  float* t1  = (float*)(ws + (size_t)N * 4);                        // reused as t2
  float* a1  = (float*)(ws + (size_t)N * 4 + (size_t)N * GCN_HID * 4);
  float* t2  = t1;

  k_deg_init<<<(N + 255) / 256, 256, 0, stream>>>(dis, N);
  k_deg_count<<<(E + 255) / 256, 256, 0, stream>>>(dst, dis, E);
  k_rsqrt<<<(N + 255) / 256, 256, 0, stream>>>(dis, N);

  // layer 1: t1 = x@W1, a1 = dis^2*t1
  k_gemm<GCN_IN_C, GCN_HID, false, false>
      <<<(N + 63) / 64, 256, 0, stream>>>(x, W1, nullptr, nullptr, dis, t1, a1, N);
  k_agg_edge<GCN_HID>
      <<<((size_t)E * (GCN_HID / 4) + 255) / 256, 256, 0, stream>>>(src, dst, t1, dis, a1, E);

  // layer 2: t2 = relu(a1+b1)@W2, out = dis^2*t2 + b2
  k_gemm<GCN_HID, GCN_OUT, true, true>
      <<<(N + 63) / 64, 256, 0, stream>>>(a1, W2, b1, b2, dis, t2, out, N);
  k_agg_edge<GCN_OUT>
      <<<((size_t)E * (GCN_OUT / 4) + 255) / 256, 256, 0, stream>>>(src, dst, t2, dis, out, E);
}

// Round 2
// 552.123 us; speedup vs baseline: 7.6230x; 7.6230x over previous
//
#include <hip/hip_runtime.h>
#include <hip/hip_bf16.h>

// GCN encoder: out = GCNconv2( relu(GCNconv1(x)) )
// GCNconv(h,W,b) = D^-1/2 (A+I) D^-1/2 (h W) + b
//
// R2: CSR-gather aggregation (no float scatter atomics).
//   build: cnt = histogram(dst); off = exscan(cnt); scatter src -> csr
//   gemm:  t_s[m] = dis[m] * (X' @ W)[m]     (dis folded into the table)
//   agg:   out[i] = dis[i] * (sum_{s in N(i)} t_s[s] + t_s[i]) (+ bias)

#define GCN_IN_C 256
#define GCN_HID  128
#define GCN_OUT  64

__global__ __launch_bounds__(256) void k_zero_i32(int* __restrict__ p, int n) {
  int i = blockIdx.x * 256 + threadIdx.x;
  if (i < n) p[i] = 0;
}

__global__ __launch_bounds__(256) void k_hist(const int* __restrict__ dst,
                                              int* __restrict__ cnt, int e) {
  int i = blockIdx.x * 256 + threadIdx.x;
  if (i < e) atomicAdd(&cnt[dst[i]], 1);
}

// per-block exclusive scan; writes local exclusive scan to off, block total to bsum
__global__ __launch_bounds__(256) void k_scan_local(const int* __restrict__ cnt,
                                                    int* __restrict__ off,
                                                    int* __restrict__ bsum, int n) {
  __shared__ int sh[256];
  int b = blockIdx.x, t = threadIdx.x, i = b * 256 + t;
  int v = (i < n) ? cnt[i] : 0;
  sh[t] = v;
  __syncthreads();
  for (int d = 1; d < 256; d <<= 1) {
    int x = (t >= d) ? sh[t - d] : 0;
    __syncthreads();
    sh[t] += x;
    __syncthreads();
  }
  if (i < n) off[i] = sh[t] - v;  // exclusive
  if (t == 255) bsum[b] = sh[255];
}

// single-block exclusive scan of block sums (nb <= 512)
__global__ __launch_bounds__(512) void k_scan_block(int* __restrict__ bsum, int nb) {
  __shared__ int sh[512];
  int t = threadIdx.x;
  int v = (t < nb) ? bsum[t] : 0;
  sh[t] = v;
  __syncthreads();
  for (int d = 1; d < 512; d <<= 1) {
    int x = (t >= d) ? sh[t - d] : 0;
    __syncthreads();
    sh[t] += x;
    __syncthreads();
  }
  if (t < nb) bsum[t] = sh[t] - v;  // exclusive
}

// off += block offset; cur = off; dis = rsqrt(cnt+1)
__global__ __launch_bounds__(256) void k_scan_fix(const int* __restrict__ cnt,
                                                  int* __restrict__ off,
                                                  int* __restrict__ cur,
                                                  const int* __restrict__ bsum,
                                                  float* __restrict__ dis, int n) {
  int b = blockIdx.x, i = b * 256 + threadIdx.x;
  if (i >= n) return;
  int o = off[i] + bsum[b];
  off[i] = o;
  cur[i] = o;
  dis[i] = rsqrtf((float)cnt[i] + 1.0f);
}

__global__ __launch_bounds__(256) void k_scatter(const int* __restrict__ src,
                                                 const int* __restrict__ dst,
                                                 int* __restrict__ cur,
                                                 int* __restrict__ csr, int e) {
  int i = blockIdx.x * 256 + threadIdx.x;
  if (i < e) {
    int p = atomicAdd(&cur[dst[i]], 1);
    csr[p] = src[i];
  }
}

// Tiled f32 GEMM: T[m] = dis[m] * (X'[m] @ W), X' = (IN_RELU_BIAS ? relu(X+inb) : X).
template<int K, int NOUT, bool IN_RELU_BIAS>
__global__ __launch_bounds__(256) void k_gemm(
    const float* __restrict__ X, const float* __restrict__ W,
    const float* __restrict__ inb, const float* __restrict__ dis,
    float* __restrict__ T, int M) {
  constexpr int BM = 64, BK = 32;
  constexpr int CPT = NOUT / 16;  // cols per thread
  __shared__ float xs[BM][BK + 1];
  __shared__ float ws[BK][NOUT];

  const int tid = threadIdx.x;
  const int m0 = blockIdx.x * BM;
  const int tx = tid & 15;
  const int ty = tid >> 4;

  float acc[4][CPT];
#pragma unroll
  for (int i = 0; i < 4; ++i)
#pragma unroll
    for (int j = 0; j < CPT; ++j) acc[i][j] = 0.0f;

  for (int k0 = 0; k0 < K; k0 += BK) {
#pragma unroll
    for (int it = 0; it < (BM * BK) / (256 * 4); ++it) {
      int f4 = tid + it * 256;
      int r = f4 >> 3;
      int c4 = f4 & 7;
      int m = m0 + r;
      float4 v = make_float4(0.f, 0.f, 0.f, 0.f);
      if (m < M) v = *(const float4*)(X + (size_t)m * K + k0 + c4 * 4);
      if (IN_RELU_BIAS) {
        int kc = k0 + c4 * 4;
        v.x = fmaxf(v.x + inb[kc + 0], 0.f);
        v.y = fmaxf(v.y + inb[kc + 1], 0.f);
        v.z = fmaxf(v.z + inb[kc + 2], 0.f);
        v.w = fmaxf(v.w + inb[kc + 3], 0.f);
      }
      xs[r][c4 * 4 + 0] = v.x;
      xs[r][c4 * 4 + 1] = v.y;
      xs[r][c4 * 4 + 2] = v.z;
      xs[r][c4 * 4 + 3] = v.w;
    }
#pragma unroll
    for (int it = 0; it < (BK * NOUT) / (256 * 4); ++it) {
      int f4 = tid + it * 256;
      int r = f4 / (NOUT / 4);
      int c4 = f4 % (NOUT / 4);
      *(float4*)(&ws[r][c4 * 4]) =
          *(const float4*)(W + (size_t)(k0 + r) * NOUT + c4 * 4);
    }
    __syncthreads();
#pragma unroll
    for (int kk = 0; kk < BK; ++kk) {
      float a[4];
#pragma unroll
      for (int i = 0; i < 4; ++i) a[i] = xs[ty * 4 + i][kk];
      float b[CPT];
#pragma unroll
      for (int j = 0; j < CPT; ++j) b[j] = ws[kk][tx * CPT + j];
#pragma unroll
      for (int i = 0; i < 4; ++i)
#pragma unroll
        for (int j = 0; j < CPT; ++j) acc[i][j] = fmaf(a[i], b[j], acc[i][j]);
    }
    __syncthreads();
  }

#pragma unroll
  for (int i = 0; i < 4; ++i) {
    int m = m0 + ty * 4 + i;
    if (m >= M) continue;
    float d = dis[m];
    size_t base = (size_t)m * NOUT + tx * CPT;
#pragma unroll
    for (int j4 = 0; j4 < CPT / 4; ++j4) {
      float4 t;
      t.x = d * acc[i][j4 * 4 + 0];
      t.y = d * acc[i][j4 * 4 + 1];
      t.z = d * acc[i][j4 * 4 + 2];
      t.w = d * acc[i][j4 * 4 + 3];
      *(float4*)(T + base + j4 * 4) = t;
    }
  }
}

// CSR gather aggregation: one wave per node.
// out[i] = dis[i] * (sum_{e in [off,end)} ts[csr[e]] + ts[i]) (+ bias)
template<int C, bool BIAS>
__global__ __launch_bounds__(256) void k_agg_csr(
    const int* __restrict__ csr, const int* __restrict__ off,
    const int* __restrict__ end, const float* __restrict__ ts,
    const float* __restrict__ dis, const float* __restrict__ bias,
    float* __restrict__ out, int n) {
  constexpr int VPL = C / 64;  // floats per lane
  int wid = (blockIdx.x * 256 + threadIdx.x) >> 6;
  int lane = threadIdx.x & 63;
  if (wid >= n) return;

  float acc[VPL];
  {
    const float* r = ts + (size_t)wid * C + lane * VPL;  // self term
    if constexpr (VPL == 2) {
      float2 v = *(const float2*)r;
      acc[0] = v.x; acc[1] = v.y;
    } else {
      acc[0] = r[0];
    }
  }
  int e = off[wid], e1 = end[wid];
  for (; e + 2 <= e1; e += 2) {  // 2-deep to double memory-level parallelism
    int s0 = csr[e], s1 = csr[e + 1];
    const float* r0 = ts + (size_t)s0 * C + lane * VPL;
    const float* r1 = ts + (size_t)s1 * C + lane * VPL;
    if constexpr (VPL == 2) {
      float2 v0 = *(const float2*)r0, v1 = *(const float2*)r1;
      acc[0] += v0.x + v1.x;
      acc[1] += v0.y + v1.y;
    } else {
      acc[0] += r0[0] + r1[0];
    }
  }
  if (e < e1) {
    int s0 = csr[e];
    const float* r0 = ts + (size_t)s0 * C + lane * VPL;
    if constexpr (VPL == 2) {
      float2 v0 = *(const float2*)r0;
      acc[0] += v0.x; acc[1] += v0.y;
    } else {
      acc[0] += r0[0];
    }
  }
  float di = dis[wid];
  float* o = out + (size_t)wid * C + lane * VPL;
#pragma unroll
  for (int j = 0; j < VPL; ++j) {
    float v = di * acc[j];
    if (BIAS) v += bias[lane * VPL + j];
    o[j] = v;
  }
}

extern "C" void kernel_launch(void* const* d_in, const int* in_sizes, int n_in,
                              void* d_out, int out_size, void* d_ws, size_t ws_size,
                              hipStream_t stream) {
  const float* x  = (const float*)d_in[0];
  const int*   ei = (const int*)d_in[1];
  const float* W1 = (const float*)d_in[2];
  const float* b1 = (const float*)d_in[3];
  const float* W2 = (const float*)d_in[4];
  const float* b2 = (const float*)d_in[5];
  float* out = (float*)d_out;

  const int N = in_sizes[0] / GCN_IN_C;  // 100000
  const int E = in_sizes[1] / 2;         // 1600000
  const int* src = ei;
  const int* dst = ei + E;
  const int NB = (N + 255) / 256;        // scan blocks (391 <= 512)

  // ws layout (all 16B aligned):
  //   dis[N] | t1s[N*128] | a1[N*128] | cnt[N] | off[N] | cur[N] | bsum[512] | csr[E]
  char* p = (char*)d_ws;
  float* dis = (float*)p;             p += (size_t)N * 4;
  float* t1s = (float*)p;             p += (size_t)N * GCN_HID * 4;
  float* a1  = (float*)p;             p += (size_t)N * GCN_HID * 4;
  int* cnt   = (int*)p;               p += (size_t)N * 4;
  int* off   = (int*)p;               p += (size_t)N * 4;
  int* cur   = (int*)p;               p += (size_t)N * 4;
  int* bsum  = (int*)p;               p += 512 * 4;
  int* csr   = (int*)p;
  float* t2s = t1s;  // layer-2 table reuses layer-1 table (row stride 64)

  // ---- CSR build
  k_zero_i32<<<NB, 256, 0, stream>>>(cnt, N);
  k_hist<<<(E + 255) / 256, 256, 0, stream>>>(dst, cnt, E);
  k_scan_local<<<NB, 256, 0, stream>>>(cnt, off, bsum, N);
  k_scan_block<<<1, 512, 0, stream>>>(bsum, NB);
  k_scan_fix<<<NB, 256, 0, stream>>>(cnt, off, cur, bsum, dis, N);
  k_scatter<<<(E + 255) / 256, 256, 0, stream>>>(src, dst, cur, csr, E);
  // after scatter, cur[i] == off[i] + cnt[i] == row end

  // ---- layer 1
  k_gemm<GCN_IN_C, GCN_HID, false>
      <<<(N + 63) / 64, 256, 0, stream>>>(x, W1, nullptr, dis, t1s, N);
  k_agg_csr<GCN_HID, false>
      <<<(N * 64 + 255) / 256, 256, 0, stream>>>(csr, off, cur, t1s, dis, nullptr, a1, N);

  // ---- layer 2
  k_gemm<GCN_HID, GCN_OUT, true>
      <<<(N + 63) / 64, 256, 0, stream>>>(a1, W2, b1, dis, t2s, N);
  k_agg_csr<GCN_OUT, true>
      <<<(N * 64 + 255) / 256, 256, 0, stream>>>(csr, off, cur, t2s, dis, b2, out, N);
}

// Round 3
// 409.082 us; speedup vs baseline: 10.2885x; 1.3497x over previous
//
#include <hip/hip_runtime.h>
#include <hip/hip_bf16.h>

// GCN encoder: out = GCNconv2( relu(GCNconv1(x)) )
// GCNconv(h,W,b) = D^-1/2 (A+I) D^-1/2 (h W) + b
//
// R3: bucketed counting-sort CSR build (no random global atomics / scans).
//   bucket b = dst >> 8  (256 nodes per bucket, B = ceil(N/256) = 391)
//   P1a: bucket histogram (LDS-aggregated)
//   scan: exclusive scan of 391 bucket sizes (1 block)
//   P1b: partition edges into bucket regions, packed (dstLocal<<24)|src
//   P2:  per-bucket block: LDS hist/scan -> off/end/dis, scatter src into
//        the bucket's contiguous csr window (single-CU writes, no amp)
//   gemm: t_s[m] = dis[m] * (X' @ W)[m]
//   agg:  out[i] = dis[i] * (sum_{s in N(i)} t_s[s] + t_s[i]) (+ bias)

#define GCN_IN_C 256
#define GCN_HID  128
#define GCN_OUT  64

#define BKT_SHIFT 8
#define BKT_NODES 256
#define EPB 4096  // edges per block in partition kernels

__global__ __launch_bounds__(256) void k_zero_i32(int* __restrict__ p, int n) {
  int i = blockIdx.x * 256 + threadIdx.x;
  if (i < n) p[i] = 0;
}

// P1a: bucket sizes
__global__ __launch_bounds__(256) void k_bucket_hist(const int* __restrict__ dst,
                                                     int* __restrict__ bcnt, int e, int nb) {
  __shared__ int h[512];
  int tid = threadIdx.x;
  h[tid] = 0; h[tid + 256] = 0;
  __syncthreads();
  int base = blockIdx.x * EPB;
#pragma unroll
  for (int j = 0; j < EPB / 256; ++j) {
    int i = base + j * 256 + tid;
    if (i < e) atomicAdd(&h[dst[i] >> BKT_SHIFT], 1);
  }
  __syncthreads();
  if (tid < nb && h[tid]) atomicAdd(&bcnt[tid], h[tid]);
  if (tid + 256 < nb && h[tid + 256]) atomicAdd(&bcnt[tid + 256], h[tid + 256]);
}

// exclusive scan of bucket sizes (nb <= 512), writes bbase and bcur
__global__ __launch_bounds__(512) void k_scan_buckets(const int* __restrict__ bcnt,
                                                      int* __restrict__ bbase,
                                                      int* __restrict__ bcur, int nb) {
  __shared__ int sh[512];
  int t = threadIdx.x;
  int v = (t < nb) ? bcnt[t] : 0;
  sh[t] = v;
  __syncthreads();
  for (int d = 1; d < 512; d <<= 1) {
    int x = (t >= d) ? sh[t - d] : 0;
    __syncthreads();
    sh[t] += x;
    __syncthreads();
  }
  if (t < nb) {
    int ex = sh[t] - v;
    bbase[t] = ex;
    bcur[t] = ex;
  }
}

// P1b: partition edges into bucket-contiguous regions (packed 4B)
__global__ __launch_bounds__(256) void k_partition(const int* __restrict__ src,
                                                   const int* __restrict__ dst,
                                                   int* __restrict__ bcur,
                                                   unsigned int* __restrict__ part,
                                                   int e, int nb) {
  __shared__ int h[512];
  __shared__ int base[512];
  int tid = threadIdx.x;
  h[tid] = 0; h[tid + 256] = 0;
  __syncthreads();
  int b0 = blockIdx.x * EPB;
  int s[EPB / 256], d[EPB / 256], rk[EPB / 256];
#pragma unroll
  for (int j = 0; j < EPB / 256; ++j) {
    int i = b0 + j * 256 + tid;
    if (i < e) {
      s[j] = src[i];
      d[j] = dst[i];
      rk[j] = atomicAdd(&h[d[j] >> BKT_SHIFT], 1);
    }
  }
  __syncthreads();
  if (tid < nb && h[tid]) base[tid] = atomicAdd(&bcur[tid], h[tid]);
  if (tid + 256 < nb && h[tid + 256]) base[tid + 256] = atomicAdd(&bcur[tid + 256], h[tid + 256]);
  __syncthreads();
#pragma unroll
  for (int j = 0; j < EPB / 256; ++j) {
    int i = b0 + j * 256 + tid;
    if (i < e) {
      int bk = d[j] >> BKT_SHIFT;
      unsigned int dl = (unsigned int)(d[j] & (BKT_NODES - 1));
      part[base[bk] + rk[j]] = (dl << 24) | (unsigned int)s[j];
    }
  }
}

// P2: per-bucket CSR finalize. One block per bucket.
__global__ __launch_bounds__(256) void k_bucket_csr(
    const unsigned int* __restrict__ part, const int* __restrict__ bbase,
    const int* __restrict__ bcnt, int* __restrict__ off, int* __restrict__ end,
    float* __restrict__ dis, int* __restrict__ csr, int n) {
  __shared__ int cnt[256];
  __shared__ int sc[256];
  __shared__ int cur[256];
  int b = blockIdx.x, tid = threadIdx.x;
  int node0 = b << BKT_SHIFT;
  int eb0 = bbase[b];
  int ebn = bcnt[b];
  cnt[tid] = 0;
  __syncthreads();
  for (int i = tid; i < ebn; i += 256) atomicAdd(&cnt[part[eb0 + i] >> 24], 1);
  __syncthreads();
  int v = cnt[tid];
  sc[tid] = v;
  __syncthreads();
  for (int dd = 1; dd < 256; dd <<= 1) {
    int x = (tid >= dd) ? sc[tid - dd] : 0;
    __syncthreads();
    sc[tid] += x;
    __syncthreads();
  }
  int lo = sc[tid] - v;  // exclusive
  cur[tid] = lo;
  int node = node0 + tid;
  if (node < n) {
    off[node] = eb0 + lo;
    end[node] = eb0 + lo + v;
    dis[node] = rsqrtf((float)v + 1.0f);
  }
  __syncthreads();
  for (int i = tid; i < ebn; i += 256) {
    unsigned int u = part[eb0 + i];
    int r = atomicAdd(&cur[u >> 24], 1);
    csr[eb0 + r] = (int)(u & 0xFFFFFFu);
  }
}

// Tiled f32 GEMM: T[m] = dis[m] * (X'[m] @ W), X' = (IN_RELU_BIAS ? relu(X+inb) : X).
template<int K, int NOUT, bool IN_RELU_BIAS>
__global__ __launch_bounds__(256) void k_gemm(
    const float* __restrict__ X, const float* __restrict__ W,
    const float* __restrict__ inb, const float* __restrict__ dis,
    float* __restrict__ T, int M) {
  constexpr int BM = 64, BK = 32;
  constexpr int CPT = NOUT / 16;  // cols per thread
  __shared__ float xs[BM][BK + 1];
  __shared__ float ws[BK][NOUT];

  const int tid = threadIdx.x;
  const int m0 = blockIdx.x * BM;
  const int tx = tid & 15;
  const int ty = tid >> 4;

  float acc[4][CPT];
#pragma unroll
  for (int i = 0; i < 4; ++i)
#pragma unroll
    for (int j = 0; j < CPT; ++j) acc[i][j] = 0.0f;

  for (int k0 = 0; k0 < K; k0 += BK) {
#pragma unroll
    for (int it = 0; it < (BM * BK) / (256 * 4); ++it) {
      int f4 = tid + it * 256;
      int r = f4 >> 3;
      int c4 = f4 & 7;
      int m = m0 + r;
      float4 v = make_float4(0.f, 0.f, 0.f, 0.f);
      if (m < M) v = *(const float4*)(X + (size_t)m * K + k0 + c4 * 4);
      if (IN_RELU_BIAS) {
        int kc = k0 + c4 * 4;
        v.x = fmaxf(v.x + inb[kc + 0], 0.f);
        v.y = fmaxf(v.y + inb[kc + 1], 0.f);
        v.z = fmaxf(v.z + inb[kc + 2], 0.f);
        v.w = fmaxf(v.w + inb[kc + 3], 0.f);
      }
      xs[r][c4 * 4 + 0] = v.x;
      xs[r][c4 * 4 + 1] = v.y;
      xs[r][c4 * 4 + 2] = v.z;
      xs[r][c4 * 4 + 3] = v.w;
    }
#pragma unroll
    for (int it = 0; it < (BK * NOUT) / (256 * 4); ++it) {
      int f4 = tid + it * 256;
      int r = f4 / (NOUT / 4);
      int c4 = f4 % (NOUT / 4);
      *(float4*)(&ws[r][c4 * 4]) =
          *(const float4*)(W + (size_t)(k0 + r) * NOUT + c4 * 4);
    }
    __syncthreads();
#pragma unroll
    for (int kk = 0; kk < BK; ++kk) {
      float a[4];
#pragma unroll
      for (int i = 0; i < 4; ++i) a[i] = xs[ty * 4 + i][kk];
      float b[CPT];
#pragma unroll
      for (int j = 0; j < CPT; ++j) b[j] = ws[kk][tx * CPT + j];
#pragma unroll
      for (int i = 0; i < 4; ++i)
#pragma unroll
        for (int j = 0; j < CPT; ++j) acc[i][j] = fmaf(a[i], b[j], acc[i][j]);
    }
    __syncthreads();
  }

#pragma unroll
  for (int i = 0; i < 4; ++i) {
    int m = m0 + ty * 4 + i;
    if (m >= M) continue;
    float d = dis[m];
    size_t base = (size_t)m * NOUT + tx * CPT;
#pragma unroll
    for (int j4 = 0; j4 < CPT / 4; ++j4) {
      float4 t;
      t.x = d * acc[i][j4 * 4 + 0];
      t.y = d * acc[i][j4 * 4 + 1];
      t.z = d * acc[i][j4 * 4 + 2];
      t.w = d * acc[i][j4 * 4 + 3];
      *(float4*)(T + base + j4 * 4) = t;
    }
  }
}

// CSR gather aggregation: one wave per node.
template<int C, bool BIAS>
__global__ __launch_bounds__(256) void k_agg_csr(
    const int* __restrict__ csr, const int* __restrict__ off,
    const int* __restrict__ end, const float* __restrict__ ts,
    const float* __restrict__ dis, const float* __restrict__ bias,
    float* __restrict__ out, int n) {
  constexpr int VPL = C / 64;  // floats per lane
  int wid = (blockIdx.x * 256 + threadIdx.x) >> 6;
  int lane = threadIdx.x & 63;
  if (wid >= n) return;

  float acc[VPL];
  {
    const float* r = ts + (size_t)wid * C + lane * VPL;  // self term
    if constexpr (VPL == 2) {
      float2 v = *(const float2*)r;
      acc[0] = v.x; acc[1] = v.y;
    } else {
      acc[0] = r[0];
    }
  }
  int e = off[wid], e1 = end[wid];
  for (; e + 2 <= e1; e += 2) {
    int s0 = csr[e], s1 = csr[e + 1];
    const float* r0 = ts + (size_t)s0 * C + lane * VPL;
    const float* r1 = ts + (size_t)s1 * C + lane * VPL;
    if constexpr (VPL == 2) {
      float2 v0 = *(const float2*)r0, v1 = *(const float2*)r1;
      acc[0] += v0.x + v1.x;
      acc[1] += v0.y + v1.y;
    } else {
      acc[0] += r0[0] + r1[0];
    }
  }
  if (e < e1) {
    int s0 = csr[e];
    const float* r0 = ts + (size_t)s0 * C + lane * VPL;
    if constexpr (VPL == 2) {
      float2 v0 = *(const float2*)r0;
      acc[0] += v0.x; acc[1] += v0.y;
    } else {
      acc[0] += r0[0];
    }
  }
  float di = dis[wid];
  float* o = out + (size_t)wid * C + lane * VPL;
#pragma unroll
  for (int j = 0; j < VPL; ++j) {
    float v = di * acc[j];
    if (BIAS) v += bias[lane * VPL + j];
    o[j] = v;
  }
}

extern "C" void kernel_launch(void* const* d_in, const int* in_sizes, int n_in,
                              void* d_out, int out_size, void* d_ws, size_t ws_size,
                              hipStream_t stream) {
  const float* x  = (const float*)d_in[0];
  const int*   ei = (const int*)d_in[1];
  const float* W1 = (const float*)d_in[2];
  const float* b1 = (const float*)d_in[3];
  const float* W2 = (const float*)d_in[4];
  const float* b2 = (const float*)d_in[5];
  float* out = (float*)d_out;

  const int N = in_sizes[0] / GCN_IN_C;  // 100000
  const int E = in_sizes[1] / 2;         // 1600000
  const int* src = ei;
  const int* dst = ei + E;
  const int NB = (N + BKT_NODES - 1) >> BKT_SHIFT;  // 391 buckets
  const int EB = (E + EPB - 1) / EPB;               // partition blocks

  // ws layout:
  //   dis[N] | t1s[N*128] | a1[N*128] | off[N] | end[N] | csr[E] | bcnt|bbase|bcur [512 each]
  //   part[E] aliases a1 (dead before agg1 writes a1)
  char* p = (char*)d_ws;
  float* dis = (float*)p;             p += (size_t)N * 4;
  float* t1s = (float*)p;             p += (size_t)N * GCN_HID * 4;
  float* a1  = (float*)p;             p += (size_t)N * GCN_HID * 4;
  int* off   = (int*)p;               p += (size_t)N * 4;
  int* end   = (int*)p;               p += (size_t)N * 4;
  int* csr   = (int*)p;               p += (size_t)E * 4;
  int* bcnt  = (int*)p;               p += 512 * 4;
  int* bbase = (int*)p;               p += 512 * 4;
  int* bcur  = (int*)p;
  unsigned int* part = (unsigned int*)a1;  // alias
  float* t2s = t1s;

  // ---- CSR build (bucketed counting sort)
  k_zero_i32<<<2, 256, 0, stream>>>(bcnt, 512);
  k_bucket_hist<<<EB, 256, 0, stream>>>(dst, bcnt, E, NB);
  k_scan_buckets<<<1, 512, 0, stream>>>(bcnt, bbase, bcur, NB);
  k_partition<<<EB, 256, 0, stream>>>(src, dst, bcur, part, E, NB);
  k_bucket_csr<<<NB, 256, 0, stream>>>(part, bbase, bcnt, off, end, dis, csr, N);

  // ---- layer 1
  k_gemm<GCN_IN_C, GCN_HID, false>
      <<<(N + 63) / 64, 256, 0, stream>>>(x, W1, nullptr, dis, t1s, N);
  k_agg_csr<GCN_HID, false>
      <<<(N * 64 + 255) / 256, 256, 0, stream>>>(csr, off, end, t1s, dis, nullptr, a1, N);

  // ---- layer 2
  k_gemm<GCN_HID, GCN_OUT, true>
      <<<(N + 63) / 64, 256, 0, stream>>>(a1, W2, b1, dis, t2s, N);
  k_agg_csr<GCN_OUT, true>
      <<<(N * 64 + 255) / 256, 256, 0, stream>>>(csr, off, end, t2s, dis, b2, out, N);
}

// Round 4
// 370.021 us; speedup vs baseline: 11.3746x; 1.1056x over previous
//
#include <hip/hip_runtime.h>
#include <hip/hip_bf16.h>

// GCN encoder: out = GCNconv2( relu(GCNconv1(x)) )
// GCNconv(h,W,b) = D^-1/2 (A+I) D^-1/2 (h W) + b
//
// R4: lane-group float4 gather aggregation (more MLP, fewer load issues).
//   agg: wave per node; G lane-groups, each group gathers whole rows with
//   float4 loads, 2-deep unrolled; cross-group shfl_xor reduce at the end.

#define GCN_IN_C 256
#define GCN_HID  128
#define GCN_OUT  64

#define BKT_SHIFT 8
#define BKT_NODES 256
#define EPB 4096  // edges per block in partition kernels

__global__ __launch_bounds__(256) void k_zero_i32(int* __restrict__ p, int n) {
  int i = blockIdx.x * 256 + threadIdx.x;
  if (i < n) p[i] = 0;
}

// P1a: bucket sizes
__global__ __launch_bounds__(256) void k_bucket_hist(const int* __restrict__ dst,
                                                     int* __restrict__ bcnt, int e, int nb) {
  __shared__ int h[512];
  int tid = threadIdx.x;
  h[tid] = 0; h[tid + 256] = 0;
  __syncthreads();
  int base = blockIdx.x * EPB;
#pragma unroll
  for (int j = 0; j < EPB / 256; ++j) {
    int i = base + j * 256 + tid;
    if (i < e) atomicAdd(&h[dst[i] >> BKT_SHIFT], 1);
  }
  __syncthreads();
  if (tid < nb && h[tid]) atomicAdd(&bcnt[tid], h[tid]);
  if (tid + 256 < nb && h[tid + 256]) atomicAdd(&bcnt[tid + 256], h[tid + 256]);
}

// exclusive scan of bucket sizes (nb <= 512), writes bbase and bcur
__global__ __launch_bounds__(512) void k_scan_buckets(const int* __restrict__ bcnt,
                                                      int* __restrict__ bbase,
                                                      int* __restrict__ bcur, int nb) {
  __shared__ int sh[512];
  int t = threadIdx.x;
  int v = (t < nb) ? bcnt[t] : 0;
  sh[t] = v;
  __syncthreads();
  for (int d = 1; d < 512; d <<= 1) {
    int x = (t >= d) ? sh[t - d] : 0;
    __syncthreads();
    sh[t] += x;
    __syncthreads();
  }
  if (t < nb) {
    int ex = sh[t] - v;
    bbase[t] = ex;
    bcur[t] = ex;
  }
}

// P1b: partition edges into bucket-contiguous regions (packed 4B)
__global__ __launch_bounds__(256) void k_partition(const int* __restrict__ src,
                                                   const int* __restrict__ dst,
                                                   int* __restrict__ bcur,
                                                   unsigned int* __restrict__ part,
                                                   int e, int nb) {
  __shared__ int h[512];
  __shared__ int base[512];
  int tid = threadIdx.x;
  h[tid] = 0; h[tid + 256] = 0;
  __syncthreads();
  int b0 = blockIdx.x * EPB;
  int s[EPB / 256], d[EPB / 256], rk[EPB / 256];
#pragma unroll
  for (int j = 0; j < EPB / 256; ++j) {
    int i = b0 + j * 256 + tid;
    if (i < e) {
      s[j] = src[i];
      d[j] = dst[i];
      rk[j] = atomicAdd(&h[d[j] >> BKT_SHIFT], 1);
    }
  }
  __syncthreads();
  if (tid < nb && h[tid]) base[tid] = atomicAdd(&bcur[tid], h[tid]);
  if (tid + 256 < nb && h[tid + 256]) base[tid + 256] = atomicAdd(&bcur[tid + 256], h[tid + 256]);
  __syncthreads();
#pragma unroll
  for (int j = 0; j < EPB / 256; ++j) {
    int i = b0 + j * 256 + tid;
    if (i < e) {
      int bk = d[j] >> BKT_SHIFT;
      unsigned int dl = (unsigned int)(d[j] & (BKT_NODES - 1));
      part[base[bk] + rk[j]] = (dl << 24) | (unsigned int)s[j];
    }
  }
}

// P2: per-bucket CSR finalize. One block per bucket.
__global__ __launch_bounds__(256) void k_bucket_csr(
    const unsigned int* __restrict__ part, const int* __restrict__ bbase,
    const int* __restrict__ bcnt, int* __restrict__ off, int* __restrict__ end,
    float* __restrict__ dis, int* __restrict__ csr, int n) {
  __shared__ int cnt[256];
  __shared__ int sc[256];
  __shared__ int cur[256];
  int b = blockIdx.x, tid = threadIdx.x;
  int node0 = b << BKT_SHIFT;
  int eb0 = bbase[b];
  int ebn = bcnt[b];
  cnt[tid] = 0;
  __syncthreads();
  for (int i = tid; i < ebn; i += 256) atomicAdd(&cnt[part[eb0 + i] >> 24], 1);
  __syncthreads();
  int v = cnt[tid];
  sc[tid] = v;
  __syncthreads();
  for (int dd = 1; dd < 256; dd <<= 1) {
    int x = (tid >= dd) ? sc[tid - dd] : 0;
    __syncthreads();
    sc[tid] += x;
    __syncthreads();
  }
  int lo = sc[tid] - v;  // exclusive
  cur[tid] = lo;
  int node = node0 + tid;
  if (node < n) {
    off[node] = eb0 + lo;
    end[node] = eb0 + lo + v;
    dis[node] = rsqrtf((float)v + 1.0f);
  }
  __syncthreads();
  for (int i = tid; i < ebn; i += 256) {
    unsigned int u = part[eb0 + i];
    int r = atomicAdd(&cur[u >> 24], 1);
    csr[eb0 + r] = (int)(u & 0xFFFFFFu);
  }
}

// Tiled f32 GEMM: T[m] = dis[m] * (X'[m] @ W), X' = (IN_RELU_BIAS ? relu(X+inb) : X).
template<int K, int NOUT, bool IN_RELU_BIAS>
__global__ __launch_bounds__(256) void k_gemm(
    const float* __restrict__ X, const float* __restrict__ W,
    const float* __restrict__ inb, const float* __restrict__ dis,
    float* __restrict__ T, int M) {
  constexpr int BM = 64, BK = 32;
  constexpr int CPT = NOUT / 16;  // cols per thread
  __shared__ float xs[BM][BK + 1];
  __shared__ float ws[BK][NOUT];

  const int tid = threadIdx.x;
  const int m0 = blockIdx.x * BM;
  const int tx = tid & 15;
  const int ty = tid >> 4;

  float acc[4][CPT];
#pragma unroll
  for (int i = 0; i < 4; ++i)
#pragma unroll
    for (int j = 0; j < CPT; ++j) acc[i][j] = 0.0f;

  for (int k0 = 0; k0 < K; k0 += BK) {
#pragma unroll
    for (int it = 0; it < (BM * BK) / (256 * 4); ++it) {
      int f4 = tid + it * 256;
      int r = f4 >> 3;
      int c4 = f4 & 7;
      int m = m0 + r;
      float4 v = make_float4(0.f, 0.f, 0.f, 0.f);
      if (m < M) v = *(const float4*)(X + (size_t)m * K + k0 + c4 * 4);
      if (IN_RELU_BIAS) {
        int kc = k0 + c4 * 4;
        v.x = fmaxf(v.x + inb[kc + 0], 0.f);
        v.y = fmaxf(v.y + inb[kc + 1], 0.f);
        v.z = fmaxf(v.z + inb[kc + 2], 0.f);
        v.w = fmaxf(v.w + inb[kc + 3], 0.f);
      }
      xs[r][c4 * 4 + 0] = v.x;
      xs[r][c4 * 4 + 1] = v.y;
      xs[r][c4 * 4 + 2] = v.z;
      xs[r][c4 * 4 + 3] = v.w;
    }
#pragma unroll
    for (int it = 0; it < (BK * NOUT) / (256 * 4); ++it) {
      int f4 = tid + it * 256;
      int r = f4 / (NOUT / 4);
      int c4 = f4 % (NOUT / 4);
      *(float4*)(&ws[r][c4 * 4]) =
          *(const float4*)(W + (size_t)(k0 + r) * NOUT + c4 * 4);
    }
    __syncthreads();
#pragma unroll
    for (int kk = 0; kk < BK; ++kk) {
      float a[4];
#pragma unroll
      for (int i = 0; i < 4; ++i) a[i] = xs[ty * 4 + i][kk];
      float b[CPT];
#pragma unroll
      for (int j = 0; j < CPT; ++j) b[j] = ws[kk][tx * CPT + j];
#pragma unroll
      for (int i = 0; i < 4; ++i)
#pragma unroll
        for (int j = 0; j < CPT; ++j) acc[i][j] = fmaf(a[i], b[j], acc[i][j]);
    }
    __syncthreads();
  }

#pragma unroll
  for (int i = 0; i < 4; ++i) {
    int m = m0 + ty * 4 + i;
    if (m >= M) continue;
    float d = dis[m];
    size_t base = (size_t)m * NOUT + tx * CPT;
#pragma unroll
    for (int j4 = 0; j4 < CPT / 4; ++j4) {
      float4 t;
      t.x = d * acc[i][j4 * 4 + 0];
      t.y = d * acc[i][j4 * 4 + 1];
      t.z = d * acc[i][j4 * 4 + 2];
      t.w = d * acc[i][j4 * 4 + 3];
      *(float4*)(T + base + j4 * 4) = t;
    }
  }
}

// CSR gather aggregation, R4: wave per node, G lane-groups of LPG lanes,
// each group gathers full rows as float4, 2-deep unrolled edge stride.
// out[i] = dis[i] * (sum_{s in N(i)} ts[s] + ts[i]) (+ bias)
template<int C, bool BIAS>
__global__ __launch_bounds__(256) void k_agg_csr(
    const int* __restrict__ csr, const int* __restrict__ off,
    const int* __restrict__ end, const float* __restrict__ ts,
    const float* __restrict__ dis, const float* __restrict__ bias,
    float* __restrict__ out, int n) {
  constexpr int LPG = C / 4;   // lanes per group: 32 (C=128), 16 (C=64)
  constexpr int G = 64 / LPG;  // groups per wave: 2, 4
  int wid = (blockIdx.x * 256 + threadIdx.x) >> 6;
  int lane = threadIdx.x & 63;
  int gid = lane / LPG;
  int gl = lane % LPG;
  if (wid >= n) return;

  float4 acc = make_float4(0.f, 0.f, 0.f, 0.f);
  if (gid == 0) acc = *(const float4*)(ts + (size_t)wid * C + gl * 4);  // self term

  int e = off[wid] + gid;
  int e1 = end[wid];
  for (; e + G < e1; e += 2 * G) {
    int s0 = csr[e];
    int s1 = csr[e + G];
    float4 v0 = *(const float4*)(ts + (size_t)s0 * C + gl * 4);
    float4 v1 = *(const float4*)(ts + (size_t)s1 * C + gl * 4);
    acc.x += v0.x + v1.x;
    acc.y += v0.y + v1.y;
    acc.z += v0.z + v1.z;
    acc.w += v0.w + v1.w;
  }
  if (e < e1) {
    int s0 = csr[e];
    float4 v0 = *(const float4*)(ts + (size_t)s0 * C + gl * 4);
    acc.x += v0.x; acc.y += v0.y; acc.z += v0.z; acc.w += v0.w;
  }

  // cross-group reduce: fold groups down to lanes [0, LPG)
#pragma unroll
  for (int w = LPG; w < 64; w <<= 1) {
    acc.x += __shfl_xor(acc.x, w);
    acc.y += __shfl_xor(acc.y, w);
    acc.z += __shfl_xor(acc.z, w);
    acc.w += __shfl_xor(acc.w, w);
  }

  if (gid == 0) {
    float di = dis[wid];
    float4 o;
    o.x = di * acc.x; o.y = di * acc.y; o.z = di * acc.z; o.w = di * acc.w;
    if (BIAS) {
      float4 bv = *(const float4*)(bias + gl * 4);
      o.x += bv.x; o.y += bv.y; o.z += bv.z; o.w += bv.w;
    }
    *(float4*)(out + (size_t)wid * C + gl * 4) = o;
  }
}

extern "C" void kernel_launch(void* const* d_in, const int* in_sizes, int n_in,
                              void* d_out, int out_size, void* d_ws, size_t ws_size,
                              hipStream_t stream) {
  const float* x  = (const float*)d_in[0];
  const int*   ei = (const int*)d_in[1];
  const float* W1 = (const float*)d_in[2];
  const float* b1 = (const float*)d_in[3];
  const float* W2 = (const float*)d_in[4];
  const float* b2 = (const float*)d_in[5];
  float* out = (float*)d_out;

  const int N = in_sizes[0] / GCN_IN_C;  // 100000
  const int E = in_sizes[1] / 2;         // 1600000
  const int* src = ei;
  const int* dst = ei + E;
  const int NB = (N + BKT_NODES - 1) >> BKT_SHIFT;  // 391 buckets
  const int EB = (E + EPB - 1) / EPB;               // partition blocks

  // ws layout:
  //   dis[N] | t1s[N*128] | a1[N*128] | off[N] | end[N] | csr[E] | bcnt|bbase|bcur [512 each]
  //   part[E] aliases a1 (dead before agg1 writes a1)
  char* p = (char*)d_ws;
  float* dis = (float*)p;             p += (size_t)N * 4;
  float* t1s = (float*)p;             p += (size_t)N * GCN_HID * 4;
  float* a1  = (float*)p;             p += (size_t)N * GCN_HID * 4;
  int* off   = (int*)p;               p += (size_t)N * 4;
  int* end   = (int*)p;               p += (size_t)N * 4;
  int* csr   = (int*)p;               p += (size_t)E * 4;
  int* bcnt  = (int*)p;               p += 512 * 4;
  int* bbase = (int*)p;               p += 512 * 4;
  int* bcur  = (int*)p;
  unsigned int* part = (unsigned int*)a1;  // alias
  float* t2s = t1s;

  // ---- CSR build (bucketed counting sort)
  k_zero_i32<<<2, 256, 0, stream>>>(bcnt, 512);
  k_bucket_hist<<<EB, 256, 0, stream>>>(dst, bcnt, E, NB);
  k_scan_buckets<<<1, 512, 0, stream>>>(bcnt, bbase, bcur, NB);
  k_partition<<<EB, 256, 0, stream>>>(src, dst, bcur, part, E, NB);
  k_bucket_csr<<<NB, 256, 0, stream>>>(part, bbase, bcnt, off, end, dis, csr, N);

  // ---- layer 1
  k_gemm<GCN_IN_C, GCN_HID, false>
      <<<(N + 63) / 64, 256, 0, stream>>>(x, W1, nullptr, dis, t1s, N);
  k_agg_csr<GCN_HID, false>
      <<<((size_t)N * 64 + 255) / 256, 256, 0, stream>>>(csr, off, end, t1s, dis, nullptr, a1, N);

  // ---- layer 2
  k_gemm<GCN_HID, GCN_OUT, true>
      <<<(N + 63) / 64, 256, 0, stream>>>(a1, W2, b1, dis, t2s, N);
  k_agg_csr<GCN_OUT, true>
      <<<((size_t)N * 64 + 255) / 256, 256, 0, stream>>>(csr, off, end, t2s, dis, b2, out, N);
}

// Round 5
// 299.062 us; speedup vs baseline: 14.0734x; 1.2373x over previous
//
#include <hip/hip_runtime.h>
#include <hip/hip_bf16.h>

// GCN encoder: out = GCNconv2( relu(GCNconv1(x)) )
// GCNconv(h,W,b) = D^-1/2 (A+I) D^-1/2 (h W) + b
//
// R5: MFMA bf16 split-precision GEMMs (3-term: ah*bh + ah*bl + al*bh).
//   W pre-split into k-step-blocked bf16 hi/lo layout [ks][hl][g][n][8];
//   A (x / a1) loaded direct from global per lane, split in-register.
//   CSR build + lane-group gather agg unchanged from R4.

#define GCN_IN_C 256
#define GCN_HID  128
#define GCN_OUT  64

#define BKT_SHIFT 8
#define BKT_NODES 256
#define EPB 4096  // edges per block in partition kernels

typedef __bf16 bf16x8 __attribute__((ext_vector_type(8)));
typedef float f32x4 __attribute__((ext_vector_type(4)));

__global__ __launch_bounds__(256) void k_zero_i32(int* __restrict__ p, int n) {
  int i = blockIdx.x * 256 + threadIdx.x;
  if (i < n) p[i] = 0;
}

// P1a: bucket sizes
__global__ __launch_bounds__(256) void k_bucket_hist(const int* __restrict__ dst,
                                                     int* __restrict__ bcnt, int e, int nb) {
  __shared__ int h[512];
  int tid = threadIdx.x;
  h[tid] = 0; h[tid + 256] = 0;
  __syncthreads();
  int base = blockIdx.x * EPB;
#pragma unroll
  for (int j = 0; j < EPB / 256; ++j) {
    int i = base + j * 256 + tid;
    if (i < e) atomicAdd(&h[dst[i] >> BKT_SHIFT], 1);
  }
  __syncthreads();
  if (tid < nb && h[tid]) atomicAdd(&bcnt[tid], h[tid]);
  if (tid + 256 < nb && h[tid + 256]) atomicAdd(&bcnt[tid + 256], h[tid + 256]);
}

// exclusive scan of bucket sizes (nb <= 512), writes bbase and bcur
__global__ __launch_bounds__(512) void k_scan_buckets(const int* __restrict__ bcnt,
                                                      int* __restrict__ bbase,
                                                      int* __restrict__ bcur, int nb) {
  __shared__ int sh[512];
  int t = threadIdx.x;
  int v = (t < nb) ? bcnt[t] : 0;
  sh[t] = v;
  __syncthreads();
  for (int d = 1; d < 512; d <<= 1) {
    int x = (t >= d) ? sh[t - d] : 0;
    __syncthreads();
    sh[t] += x;
    __syncthreads();
  }
  if (t < nb) {
    int ex = sh[t] - v;
    bbase[t] = ex;
    bcur[t] = ex;
  }
}

// P1b: partition edges into bucket-contiguous regions (packed 4B)
__global__ __launch_bounds__(256) void k_partition(const int* __restrict__ src,
                                                   const int* __restrict__ dst,
                                                   int* __restrict__ bcur,
                                                   unsigned int* __restrict__ part,
                                                   int e, int nb) {
  __shared__ int h[512];
  __shared__ int base[512];
  int tid = threadIdx.x;
  h[tid] = 0; h[tid + 256] = 0;
  __syncthreads();
  int b0 = blockIdx.x * EPB;
  int s[EPB / 256], d[EPB / 256], rk[EPB / 256];
#pragma unroll
  for (int j = 0; j < EPB / 256; ++j) {
    int i = b0 + j * 256 + tid;
    if (i < e) {
      s[j] = src[i];
      d[j] = dst[i];
      rk[j] = atomicAdd(&h[d[j] >> BKT_SHIFT], 1);
    }
  }
  __syncthreads();
  if (tid < nb && h[tid]) base[tid] = atomicAdd(&bcur[tid], h[tid]);
  if (tid + 256 < nb && h[tid + 256]) base[tid + 256] = atomicAdd(&bcur[tid + 256], h[tid + 256]);
  __syncthreads();
#pragma unroll
  for (int j = 0; j < EPB / 256; ++j) {
    int i = b0 + j * 256 + tid;
    if (i < e) {
      int bk = d[j] >> BKT_SHIFT;
      unsigned int dl = (unsigned int)(d[j] & (BKT_NODES - 1));
      part[base[bk] + rk[j]] = (dl << 24) | (unsigned int)s[j];
    }
  }
}

// P2: per-bucket CSR finalize. One block per bucket.
__global__ __launch_bounds__(256) void k_bucket_csr(
    const unsigned int* __restrict__ part, const int* __restrict__ bbase,
    const int* __restrict__ bcnt, int* __restrict__ off, int* __restrict__ end,
    float* __restrict__ dis, int* __restrict__ csr, int n) {
  __shared__ int cnt[256];
  __shared__ int sc[256];
  __shared__ int cur[256];
  int b = blockIdx.x, tid = threadIdx.x;
  int node0 = b << BKT_SHIFT;
  int eb0 = bbase[b];
  int ebn = bcnt[b];
  cnt[tid] = 0;
  __syncthreads();
  for (int i = tid; i < ebn; i += 256) atomicAdd(&cnt[part[eb0 + i] >> 24], 1);
  __syncthreads();
  int v = cnt[tid];
  sc[tid] = v;
  __syncthreads();
  for (int dd = 1; dd < 256; dd <<= 1) {
    int x = (tid >= dd) ? sc[tid - dd] : 0;
    __syncthreads();
    sc[tid] += x;
    __syncthreads();
  }
  int lo = sc[tid] - v;  // exclusive
  cur[tid] = lo;
  int node = node0 + tid;
  if (node < n) {
    off[node] = eb0 + lo;
    end[node] = eb0 + lo + v;
    dis[node] = rsqrtf((float)v + 1.0f);
  }
  __syncthreads();
  for (int i = tid; i < ebn; i += 256) {
    unsigned int u = part[eb0 + i];
    int r = atomicAdd(&cur[u >> 24], 1);
    csr[eb0 + r] = (int)(u & 0xFFFFFFu);
  }
}

// Pre-split W (K x NOUT, f32) into k-step-blocked bf16 hi/lo:
//   Wsp[ks][hl][g][n][8] ; k = ks*32 + g*8 + j
template<int K, int NOUT>
__global__ __launch_bounds__(256) void k_split_w(const float* __restrict__ W,
                                                 __bf16* __restrict__ Wsp) {
  constexpr int KSTEPS = K / 32;
  int idx = blockIdx.x * 256 + threadIdx.x;  // (ks, g, n)
  if (idx >= KSTEPS * 4 * NOUT) return;
  int n = idx % NOUT;
  int g = (idx / NOUT) & 3;
  int ks = idx / (4 * NOUT);
  __bf16* hi = Wsp + (size_t)ks * (2 * 4 * NOUT * 8) + ((size_t)g * NOUT + n) * 8;
  __bf16* lo = hi + 4 * NOUT * 8;
#pragma unroll
  for (int j = 0; j < 8; ++j) {
    float f = W[(size_t)(ks * 32 + g * 8 + j) * NOUT + n];
    __bf16 h = (__bf16)f;
    hi[j] = h;
    lo[j] = (__bf16)(f - (float)h);
  }
}

// MFMA split-bf16 GEMM: T[m] = dis[m] * (X'[m] @ W), X' = relu(X+inb) if flagged.
// BM=128, 4 waves x 32 rows, full NOUT width. B staged in LDS (double buffer),
// A loaded direct from global per lane and split in-register.
template<int K, int NOUT, bool IN_RELU_BIAS>
__global__ __launch_bounds__(256) void k_gemm_mfma(
    const float* __restrict__ X, const __bf16* __restrict__ Wsp,
    const float* __restrict__ inb, const float* __restrict__ dis,
    float* __restrict__ T, int M) {
  constexpr int BM = 128;
  constexpr int NF = NOUT / 16;        // n-frags per wave
  constexpr int KSTEPS = K / 32;
  constexpr int TILE = 2 * 4 * NOUT * 8;   // bf16 elems per kstep (hi+lo)
  constexpr int GRAN = TILE * 2 / 16;      // 16B granules per kstep
  constexpr int GPT = GRAN / 256;          // granules per thread
  __shared__ __bf16 blds[2][TILE];

  const int tid = threadIdx.x;
  const int wave = tid >> 6;
  const int lane = tid & 63;
  const int l15 = lane & 15;
  const int lg = lane >> 4;                 // k-group 0..3
  const int r0w = blockIdx.x * BM + wave * 32;

  f32x4 acc[2][NF];
#pragma unroll
  for (int mf = 0; mf < 2; ++mf)
#pragma unroll
    for (int nf = 0; nf < NF; ++nf) acc[mf][nf] = (f32x4){0.f, 0.f, 0.f, 0.f};

  int rowA[2];
#pragma unroll
  for (int mf = 0; mf < 2; ++mf) {
    int r = r0w + mf * 16 + l15;
    rowA[mf] = (r < M) ? r : (M - 1);  // clamp: OOB rows never stored
  }

  const uint4* gW = (const uint4*)Wsp;
  // prologue: stage kstep 0 into buf 0
  {
    uint4* dst4 = (uint4*)&blds[0][0];
#pragma unroll
    for (int i = 0; i < GPT; ++i) dst4[tid + i * 256] = gW[tid + i * 256];
  }
  __syncthreads();

  int cur = 0;
  for (int ks = 0; ks < KSTEPS; ++ks) {
    uint4 sreg[GPT];
    if (ks + 1 < KSTEPS) {
#pragma unroll
      for (int i = 0; i < GPT; ++i)
        sreg[i] = gW[(size_t)(ks + 1) * GPT * 256 + tid + i * 256];
    }
    // ---- A fragments: load f32, optional relu+bias, split hi/lo in regs
    bf16x8 ah[2], al[2];
    const int k0 = ks * 32 + lg * 8;
#pragma unroll
    for (int mf = 0; mf < 2; ++mf) {
      const float* ap = X + (size_t)rowA[mf] * K + k0;
      float4 v0 = *(const float4*)ap;
      float4 v1 = *(const float4*)(ap + 4);
      float va[8] = {v0.x, v0.y, v0.z, v0.w, v1.x, v1.y, v1.z, v1.w};
      if (IN_RELU_BIAS) {
        float4 bb0 = *(const float4*)(inb + k0);
        float4 bb1 = *(const float4*)(inb + k0 + 4);
        float bb[8] = {bb0.x, bb0.y, bb0.z, bb0.w, bb1.x, bb1.y, bb1.z, bb1.w};
#pragma unroll
        for (int j = 0; j < 8; ++j) va[j] = fmaxf(va[j] + bb[j], 0.f);
      }
#pragma unroll
      for (int j = 0; j < 8; ++j) {
        __bf16 h = (__bf16)va[j];
        ah[mf][j] = h;
        al[mf][j] = (__bf16)(va[j] - (float)h);
      }
    }
    // ---- B fragments from LDS + MFMA (3-term split)
    const __bf16* bh_base = &blds[cur][0];
    const __bf16* bl_base = &blds[cur][4 * NOUT * 8];
    const int boff = lg * NOUT * 8 + l15 * 8;
#pragma unroll
    for (int nf = 0; nf < NF; ++nf) {
      bf16x8 bh = *(const bf16x8*)(bh_base + boff + nf * 128);
      bf16x8 bl = *(const bf16x8*)(bl_base + boff + nf * 128);
#pragma unroll
      for (int mf = 0; mf < 2; ++mf) {
        acc[mf][nf] = __builtin_amdgcn_mfma_f32_16x16x32_bf16(ah[mf], bh, acc[mf][nf], 0, 0, 0);
        acc[mf][nf] = __builtin_amdgcn_mfma_f32_16x16x32_bf16(ah[mf], bl, acc[mf][nf], 0, 0, 0);
        acc[mf][nf] = __builtin_amdgcn_mfma_f32_16x16x32_bf16(al[mf], bh, acc[mf][nf], 0, 0, 0);
      }
    }
    if (ks + 1 < KSTEPS) {
      uint4* dst4 = (uint4*)&blds[cur ^ 1][0];
#pragma unroll
      for (int i = 0; i < GPT; ++i) dst4[tid + i * 256] = sreg[i];
    }
    __syncthreads();
    cur ^= 1;
  }

  // ---- epilogue: C[col=l15, row=lg*4+r]; T[m] = dis[m] * acc
#pragma unroll
  for (int mf = 0; mf < 2; ++mf) {
    int rbase = r0w + mf * 16 + lg * 4;
    float dv[4];
#pragma unroll
    for (int r = 0; r < 4; ++r) dv[r] = (rbase + r < M) ? dis[rbase + r] : 0.f;
#pragma unroll
    for (int nf = 0; nf < NF; ++nf) {
#pragma unroll
      for (int r = 0; r < 4; ++r) {
        int rr = rbase + r;
        if (rr < M) T[(size_t)rr * NOUT + nf * 16 + l15] = dv[r] * acc[mf][nf][r];
      }
    }
  }
}

// CSR gather aggregation: wave per node, G lane-groups of LPG lanes,
// each group gathers full rows as float4, 2-deep unrolled edge stride.
template<int C, bool BIAS>
__global__ __launch_bounds__(256) void k_agg_csr(
    const int* __restrict__ csr, const int* __restrict__ off,
    const int* __restrict__ end, const float* __restrict__ ts,
    const float* __restrict__ dis, const float* __restrict__ bias,
    float* __restrict__ out, int n) {
  constexpr int LPG = C / 4;   // lanes per group
  constexpr int G = 64 / LPG;  // groups per wave
  int wid = (blockIdx.x * 256 + threadIdx.x) >> 6;
  int lane = threadIdx.x & 63;
  int gid = lane / LPG;
  int gl = lane % LPG;
  if (wid >= n) return;

  float4 acc = make_float4(0.f, 0.f, 0.f, 0.f);
  if (gid == 0) acc = *(const float4*)(ts + (size_t)wid * C + gl * 4);  // self term

  int e = off[wid] + gid;
  int e1 = end[wid];
  for (; e + G < e1; e += 2 * G) {
    int s0 = csr[e];
    int s1 = csr[e + G];
    float4 v0 = *(const float4*)(ts + (size_t)s0 * C + gl * 4);
    float4 v1 = *(const float4*)(ts + (size_t)s1 * C + gl * 4);
    acc.x += v0.x + v1.x;
    acc.y += v0.y + v1.y;
    acc.z += v0.z + v1.z;
    acc.w += v0.w + v1.w;
  }
  if (e < e1) {
    int s0 = csr[e];
    float4 v0 = *(const float4*)(ts + (size_t)s0 * C + gl * 4);
    acc.x += v0.x; acc.y += v0.y; acc.z += v0.z; acc.w += v0.w;
  }

#pragma unroll
  for (int w = LPG; w < 64; w <<= 1) {
    acc.x += __shfl_xor(acc.x, w);
    acc.y += __shfl_xor(acc.y, w);
    acc.z += __shfl_xor(acc.z, w);
    acc.w += __shfl_xor(acc.w, w);
  }

  if (gid == 0) {
    float di = dis[wid];
    float4 o;
    o.x = di * acc.x; o.y = di * acc.y; o.z = di * acc.z; o.w = di * acc.w;
    if (BIAS) {
      float4 bv = *(const float4*)(bias + gl * 4);
      o.x += bv.x; o.y += bv.y; o.z += bv.z; o.w += bv.w;
    }
    *(float4*)(out + (size_t)wid * C + gl * 4) = o;
  }
}

extern "C" void kernel_launch(void* const* d_in, const int* in_sizes, int n_in,
                              void* d_out, int out_size, void* d_ws, size_t ws_size,
                              hipStream_t stream) {
  const float* x  = (const float*)d_in[0];
  const int*   ei = (const int*)d_in[1];
  const float* W1 = (const float*)d_in[2];
  const float* b1 = (const float*)d_in[3];
  const float* W2 = (const float*)d_in[4];
  const float* b2 = (const float*)d_in[5];
  float* out = (float*)d_out;

  const int N = in_sizes[0] / GCN_IN_C;  // 100000
  const int E = in_sizes[1] / 2;         // 1600000
  const int* src = ei;
  const int* dst = ei + E;
  const int NB = (N + BKT_NODES - 1) >> BKT_SHIFT;  // 391 buckets
  const int EB = (E + EPB - 1) / EPB;               // partition blocks

  // ws layout:
  //   dis[N] | t1s[N*128] | a1[N*128] | off[N] | end[N] | csr[E]
  //   | bcnt|bbase|bcur [512 each] | w1sp | w2sp
  //   part[E] aliases a1 (dead before agg1 writes a1)
  char* p = (char*)d_ws;
  float* dis = (float*)p;             p += (size_t)N * 4;
  float* t1s = (float*)p;             p += (size_t)N * GCN_HID * 4;
  float* a1  = (float*)p;             p += (size_t)N * GCN_HID * 4;
  int* off   = (int*)p;               p += (size_t)N * 4;
  int* end   = (int*)p;               p += (size_t)N * 4;
  int* csr   = (int*)p;               p += (size_t)E * 4;
  int* bcnt  = (int*)p;               p += 512 * 4;
  int* bbase = (int*)p;               p += 512 * 4;
  int* bcur  = (int*)p;               p += 512 * 4;
  __bf16* w1sp = (__bf16*)p;          p += (size_t)(GCN_IN_C / 32) * 2 * 4 * GCN_HID * 8 * 2;
  __bf16* w2sp = (__bf16*)p;
  unsigned int* part = (unsigned int*)a1;  // alias
  float* t2s = t1s;

  // ---- weight pre-split (bf16 hi/lo, k-step-blocked)
  k_split_w<GCN_IN_C, GCN_HID>
      <<<((GCN_IN_C / 32) * 4 * GCN_HID + 255) / 256, 256, 0, stream>>>(W1, w1sp);
  k_split_w<GCN_HID, GCN_OUT>
      <<<((GCN_HID / 32) * 4 * GCN_OUT + 255) / 256, 256, 0, stream>>>(W2, w2sp);

  // ---- CSR build (bucketed counting sort)
  k_zero_i32<<<2, 256, 0, stream>>>(bcnt, 512);
  k_bucket_hist<<<EB, 256, 0, stream>>>(dst, bcnt, E, NB);
  k_scan_buckets<<<1, 512, 0, stream>>>(bcnt, bbase, bcur, NB);
  k_partition<<<EB, 256, 0, stream>>>(src, dst, bcur, part, E, NB);
  k_bucket_csr<<<NB, 256, 0, stream>>>(part, bbase, bcnt, off, end, dis, csr, N);

  // ---- layer 1
  k_gemm_mfma<GCN_IN_C, GCN_HID, false>
      <<<(N + 127) / 128, 256, 0, stream>>>(x, w1sp, nullptr, dis, t1s, N);
  k_agg_csr<GCN_HID, false>
      <<<((size_t)N * 64 + 255) / 256, 256, 0, stream>>>(csr, off, end, t1s, dis, nullptr, a1, N);

  // ---- layer 2
  k_gemm_mfma<GCN_HID, GCN_OUT, true>
      <<<(N + 127) / 128, 256, 0, stream>>>(a1, w2sp, b1, dis, t2s, N);
  k_agg_csr<GCN_OUT, true>
      <<<((size_t)N * 64 + 255) / 256, 256, 0, stream>>>(csr, off, end, t2s, dis, b2, out, N);
}